// Round 6
// baseline (36.270 us; speedup 1.0000x reference)
//
#include <hip/hip_runtime.h>
#include <math.h>

#define BROWS 16384
#define NCLASS 1000
#define NF4 250            // float4 chunks per row (1000/4)
#define IGNORE_INDEX (-100)

// Branchless broadcast of x[t]: dynamic register select + readlane (SGPR result).
__device__ __forceinline__ float bcast_val(float4 q0, float4 q1, float4 q2, float4 q3,
                                           int t_s)
{
    const int idx4     = t_s >> 2;
    const int lane_src = idx4 & 63;
    const int kt       = idx4 >> 6;
    const int et       = t_s & 3;
    const float4 dk  = (kt == 0) ? q0 : (kt == 1) ? q1 : (kt == 2) ? q2 : q3;
    const float cand = (et == 0) ? dk.x : (et == 1) ? dk.y : (et == 2) ? dk.z : dk.w;
    return __int_as_float(__builtin_amdgcn_readlane(__float_as_int(cand), lane_src));
}

// rank(t) = #{j: p[j] > p[t]} + #{j: p[j] == p[t] && j < t}, via 16
// ballot+popcount. Branchless; out-of-range t folds to IGNORE via scalar select.
__device__ __forceinline__ int rank_stage(float4 q0, float4 q1, float4 q2, float4 q3,
                                          int t, int lane)
{
    const bool tin = (t >= 0) && (t < NCLASS);   // wave-uniform
    const int  tc  = tin ? t : 0;
    const float v  = bcast_val(q0, q1, q2, q3, tc);

    const int j0 = (lane)       * 4;
    const int j1 = (64  + lane) * 4;
    const int j2 = (128 + lane) * 4;
    const int j3 = (192 + lane) * 4;

    int cnt = 0;
#define BAL(Q, C, JB, OFS)                                                      \
    cnt += __popcll(__ballot(((Q).C > v) || ((Q).C == v && ((JB)+(OFS)) < tc)));
    BAL(q0, x, j0, 0) BAL(q0, y, j0, 1) BAL(q0, z, j0, 2) BAL(q0, w, j0, 3)
    BAL(q1, x, j1, 0) BAL(q1, y, j1, 1) BAL(q1, z, j1, 2) BAL(q1, w, j1, 3)
    BAL(q2, x, j2, 0) BAL(q2, y, j2, 1) BAL(q2, z, j2, 2) BAL(q2, w, j2, 3)
    BAL(q3, x, j3, 0) BAL(q3, y, j3, 1) BAL(q3, z, j3, 2) BAL(q3, w, j3, 3)
#undef BAL
    return tin ? cnt : IGNORE_INDEX;
}

// __launch_bounds__(256, 1): drop the scheduler's occupancy/register-pressure
// target (R3-R5: it kept VGPR at 28-32 by re-serializing the load bursts).
// Two rows per wave: 24 independent dwordx4 in flight, two independent
// t-chains interleaved for ILP.
__global__ __launch_bounds__(256, 1) void TopKBaseLoss_80281528697452_kernel(
    const float* __restrict__ x0,
    const float* __restrict__ x1,
    const float* __restrict__ x2,
    const int*   __restrict__ target,
    int*         __restrict__ out)
{
    const int wid  = blockIdx.x * 4 + (threadIdx.x >> 6);   // 0 .. BROWS/2-1
    const int lane = threadIdx.x & 63;
    const int rowA = wid * 2;
    const int rowB = rowA + 1;

    const int tA0 = __builtin_amdgcn_readfirstlane(target[rowA]);
    const int tB0 = __builtin_amdgcn_readfirstlane(target[rowB]);

    const float4* __restrict__ rA0 = (const float4*)(x0 + (long)rowA * NCLASS);
    const float4* __restrict__ rA1 = (const float4*)(x1 + (long)rowA * NCLASS);
    const float4* __restrict__ rA2 = (const float4*)(x2 + (long)rowA * NCLASS);
    const float4* __restrict__ rB0 = (const float4*)(x0 + (long)rowB * NCLASS);
    const float4* __restrict__ rB1 = (const float4*)(x1 + (long)rowB * NCLASS);
    const float4* __restrict__ rB2 = (const float4*)(x2 + (long)rowB * NCLASS);

    const float NEG = -INFINITY;        // pad can never count: v is finite
    const float4 pad = make_float4(NEG, NEG, NEG, NEG);

    const int i0 = lane, i1 = 64 + lane, i2 = 128 + lane;
    const int i3 = 192 + lane;
    const bool ok3 = (i3 < NF4);                 // lane < 58
    const int i3c = ok3 ? i3 : (NF4 - 1);        // clamped address, value fixed below

    // 24 independent dwordx4 loads into NAMED registers — max MLP.
    float4 a0 = rA0[i0], a1 = rA0[i1], a2 = rA0[i2], a3t = rA0[i3c];
    float4 d0 = rB0[i0], d1 = rB0[i1], d2 = rB0[i2], d3t = rB0[i3c];
    float4 b0 = rA1[i0], b1 = rA1[i1], b2 = rA1[i2], b3t = rA1[i3c];
    float4 e0 = rB1[i0], e1 = rB1[i1], e2 = rB1[i2], e3t = rB1[i3c];
    float4 c0 = rA2[i0], c1 = rA2[i1], c2 = rA2[i2], c3t = rA2[i3c];
    float4 f0 = rB2[i0], f1 = rB2[i1], f2 = rB2[i2], f3t = rB2[i3c];
    const float4 a3 = ok3 ? a3t : pad;
    const float4 d3 = ok3 ? d3t : pad;
    const float4 b3 = ok3 ? b3t : pad;
    const float4 e3 = ok3 ? e3t : pad;
    const float4 c3 = ok3 ? c3t : pad;
    const float4 f3 = ok3 ? f3t : pad;

    __builtin_amdgcn_sched_barrier(0);

    // Two independent stage chains, interleaved for ILP.
    const int tA1 = rank_stage(a0, a1, a2, a3, tA0, lane);
    const int tB1 = rank_stage(d0, d1, d2, d3, tB0, lane);
    const int tA2 = rank_stage(b0, b1, b2, b3, tA1, lane);
    const int tB2 = rank_stage(e0, e1, e2, e3, tB1, lane);
    const int tA3 = rank_stage(c0, c1, c2, c3, tA2, lane);
    const int tB3 = rank_stage(f0, f1, f2, f3, tB2, lane);

    if (lane == 0) {
        out[rowA]             = tA0;
        out[BROWS + rowA]     = tA1;
        out[2 * BROWS + rowA] = tA2;
        out[3 * BROWS + rowA] = tA3;
        out[rowB]             = tB0;
        out[BROWS + rowB]     = tB1;
        out[2 * BROWS + rowB] = tB2;
        out[3 * BROWS + rowB] = tB3;
    }
}

extern "C" void kernel_launch(void* const* d_in, const int* in_sizes, int n_in,
                              void* d_out, int out_size, void* d_ws, size_t ws_size,
                              hipStream_t stream) {
    const float* x0     = (const float*)d_in[0];
    const float* x1     = (const float*)d_in[1];
    const float* x2     = (const float*)d_in[2];
    // d_in[3] (x3) is never used by the reference's outputs.
    const int*   target = (const int*)d_in[4];
    int*         out    = (int*)d_out;

    const int grid = (BROWS / 2) / 4;   // 8192 waves, 4 per 256-thread block
    TopKBaseLoss_80281528697452_kernel<<<grid, 256, 0, stream>>>(x0, x1, x2, target, out);
}

// Round 7
// 35.269 us; speedup vs baseline: 1.0284x; 1.0284x over previous
//
#include <hip/hip_runtime.h>
#include <math.h>

#define BROWS 16384
#define NCLASS 1000
#define NF4 250            // float4 chunks per row (1000/4)
#define IGNORE_INDEX (-100)

typedef float f32x4 __attribute__((ext_vector_type(4)));

// Branchless broadcast of x[t]: dynamic register select + readlane (SGPR result).
__device__ __forceinline__ float bcast_val(f32x4 q0, f32x4 q1, f32x4 q2, f32x4 q3,
                                           int t_s)
{
    const int idx4     = t_s >> 2;
    const int lane_src = idx4 & 63;
    const int kt       = idx4 >> 6;
    const int et       = t_s & 3;
    const f32x4 dk   = (kt == 0) ? q0 : (kt == 1) ? q1 : (kt == 2) ? q2 : q3;
    const float cand = (et == 0) ? dk[0] : (et == 1) ? dk[1] : (et == 2) ? dk[2] : dk[3];
    return __int_as_float(__builtin_amdgcn_readlane(__float_as_int(cand), lane_src));
}

// rank(t) = #{j: p[j] > p[t]} + #{j: p[j] == p[t] && j < t}, via 16
// ballot+popcount. Branchless; out-of-range t folds to IGNORE via scalar select.
__device__ __forceinline__ int rank_stage(f32x4 q0, f32x4 q1, f32x4 q2, f32x4 q3,
                                          int t, int lane)
{
    const bool tin = (t >= 0) && (t < NCLASS);   // wave-uniform
    const int  tc  = tin ? t : 0;
    const float v  = bcast_val(q0, q1, q2, q3, tc);

    const int j0 = (lane)       * 4;
    const int j1 = (64  + lane) * 4;
    const int j2 = (128 + lane) * 4;
    const int j3 = (192 + lane) * 4;

    int cnt = 0;
#define BAL(Q, E, JB)                                                           \
    cnt += __popcll(__ballot(((Q)[E] > v) || ((Q)[E] == v && ((JB)+(E)) < tc)));
    BAL(q0, 0, j0) BAL(q0, 1, j0) BAL(q0, 2, j0) BAL(q0, 3, j0)
    BAL(q1, 0, j1) BAL(q1, 1, j1) BAL(q1, 2, j1) BAL(q1, 3, j1)
    BAL(q2, 0, j2) BAL(q2, 1, j2) BAL(q2, 2, j2) BAL(q2, 3, j2)
    BAL(q3, 0, j3) BAL(q3, 1, j3) BAL(q3, 2, j3) BAL(q3, 3, j3)
#undef BAL
    return tin ? cnt : IGNORE_INDEX;
}

// R5 structure (best: 34.7 us): 1 row/wave, 4 waves/block, single basic block.
// New: x2's stream is loaded NON-TEMPORALLY so it doesn't evict x0/x1 from the
// 256 MB Infinity Cache across graph replays (x0+x1 = 131 MB fits; adding x2
// pushed the replay working set past L3 and capped the hit rate at ~51%).
__global__ __launch_bounds__(256) void TopKBaseLoss_80281528697452_kernel(
    const float* __restrict__ x0,
    const float* __restrict__ x1,
    const float* __restrict__ x2,
    const int*   __restrict__ target,
    int*         __restrict__ out)
{
    const int row  = blockIdx.x * 4 + (threadIdx.x >> 6);
    const int lane = threadIdx.x & 63;

    const int t0 = __builtin_amdgcn_readfirstlane(target[row]);  // uniform SGPR

    const f32x4* __restrict__ r0 = (const f32x4*)(x0 + (long)row * NCLASS);
    const f32x4* __restrict__ r1 = (const f32x4*)(x1 + (long)row * NCLASS);
    const f32x4* __restrict__ r2 = (const f32x4*)(x2 + (long)row * NCLASS);

    const float NEG = -INFINITY;        // pad can never count: v is finite
    const f32x4 pad = {NEG, NEG, NEG, NEG};

    const int i0 = lane, i1 = 64 + lane, i2 = 128 + lane;
    const int i3 = 192 + lane;
    const bool ok3 = (i3 < NF4);                 // lane < 58
    const int i3c = ok3 ? i3 : (NF4 - 1);        // clamped address, value fixed below

    // 12 independent dwordx4 loads into NAMED registers.
    f32x4 a0 = r0[i0], a1 = r0[i1], a2 = r0[i2], a3t = r0[i3c];
    f32x4 b0 = r1[i0], b1 = r1[i1], b2 = r1[i2], b3t = r1[i3c];
    // x2: non-temporal (nt) — stream from HBM, don't thrash L3 retention of x0/x1.
    f32x4 c0  = __builtin_nontemporal_load(&r2[i0]);
    f32x4 c1  = __builtin_nontemporal_load(&r2[i1]);
    f32x4 c2  = __builtin_nontemporal_load(&r2[i2]);
    f32x4 c3t = __builtin_nontemporal_load(&r2[i3c]);
    const f32x4 a3 = ok3 ? a3t : pad;
    const f32x4 b3 = ok3 ? b3t : pad;
    const f32x4 c3 = ok3 ? c3t : pad;

    __builtin_amdgcn_sched_barrier(0);

    const int t1 = rank_stage(a0, a1, a2, a3, t0, lane);
    const int t2 = rank_stage(b0, b1, b2, b3, t1, lane);
    const int t3 = rank_stage(c0, c1, c2, c3, t2, lane);

    if (lane == 0) {
        out[row]             = t0;
        out[BROWS + row]     = t1;
        out[2 * BROWS + row] = t2;
        out[3 * BROWS + row] = t3;
    }
}

extern "C" void kernel_launch(void* const* d_in, const int* in_sizes, int n_in,
                              void* d_out, int out_size, void* d_ws, size_t ws_size,
                              hipStream_t stream) {
    const float* x0     = (const float*)d_in[0];
    const float* x1     = (const float*)d_in[1];
    const float* x2     = (const float*)d_in[2];
    // d_in[3] (x3) is never used by the reference's outputs.
    const int*   target = (const int*)d_in[4];
    int*         out    = (int*)d_out;

    const int grid = BROWS / 4;         // 4096 blocks, 4 waves (rows) per block
    TopKBaseLoss_80281528697452_kernel<<<grid, 256, 0, stream>>>(x0, x1, x2, target, out);
}